// Round 4
// baseline (426.995 us; speedup 1.0000x reference)
//
#include <hip/hip_runtime.h>

#define NNODES 100000
#define NEDGES 3200000
#define FEAT 32
#define NITER 5
#define NF (NNODES * FEAT)

#define SCAN_BLK 1024
#define NB1 98              // ceil(100000/1024); 98*1024 = 100352
#define NPAD (NB1 * SCAN_BLK)
#define EDGE_BLOCKS (NEDGES / 256)           // 12500, exact
#define NPART 8
#define DPP 12500                            // dsts per partition (100000/8, exact)
#define BPP 1563                             // blocks per partition: 1563*2048 >= NEDGES
#define CHUNK 2048

// ---- pass A: per-edge weight + masked dst array + masked-weight partials ----
// dstm[e] = dst if unmasked else -1 ; wbuf[e] = w ; S_part[b] = sum of masked w
__global__ void ws_kernel(const int* __restrict__ edge_index,
                          const int* __restrict__ edge_mask,
                          const float* __restrict__ edge_scale,
                          const float* __restrict__ pert_mask,
                          const float* __restrict__ edge_weight,
                          int* __restrict__ dstm,
                          int* __restrict__ wbuf,
                          float* __restrict__ S_part) {
    const int e = blockIdx.x * 256 + threadIdx.x;   // grid covers NEDGES exactly
    const int m = edge_mask[e];
    const float w = (edge_weight[e] * (1.0f - pert_mask[e]) + pert_mask[e]) * edge_scale[e];
    wbuf[e] = __float_as_int(w);
    dstm[e] = m ? edge_index[NEDGES + e] : -1;
    float ms = m ? 0.0f : w;
    __shared__ float s[256];
    s[threadIdx.x] = ms;
    __syncthreads();
    for (int off = 128; off; off >>= 1) {
        if (threadIdx.x < off) s[threadIdx.x] += s[threadIdx.x + off];
        __syncthreads();
    }
    if (threadIdx.x == 0) S_part[blockIdx.x] = s[0];
}

// ---- deterministic reduce of S partials ----
__global__ void sreduce_kernel(const float* __restrict__ S_part, float* __restrict__ S) {
    __shared__ float s[1024];
    float a = 0.0f;
    for (int i = threadIdx.x; i < EDGE_BLOCKS; i += 1024) a += S_part[i];
    s[threadIdx.x] = a;
    __syncthreads();
    for (int off = 512; off; off >>= 1) {
        if (threadIdx.x < off) s[threadIdx.x] += s[threadIdx.x + off];
        __syncthreads();
    }
    if (threadIdx.x == 0) *S = s[0];
}

// ---- XCD-partitioned histogram: partition r (= bid&7) counts dst in its 12500-range ----
__global__ void hist8_kernel(const int* __restrict__ dstm, int* __restrict__ counts) {
    const int r = blockIdx.x & 7;
    const int c = blockIdx.x >> 3;
    const int lo = r * DPP, hi = lo + DPP;
    const int base = c * CHUNK;
    #pragma unroll
    for (int k = 0; k < CHUNK / 256; ++k) {
        const int e = base + k * 256 + threadIdx.x;
        if (e < NEDGES) {
            const int d = dstm[e];
            if (d >= lo && d < hi) atomicAdd(&counts[d], 1);
        }
    }
}

// ---- scan stage 1: per-block sums ----
__global__ void scan1_kernel(const int* __restrict__ counts, int* __restrict__ bsum) {
    __shared__ int s[SCAN_BLK];
    const int i = blockIdx.x * SCAN_BLK + threadIdx.x;
    s[threadIdx.x] = counts[i];
    __syncthreads();
    for (int off = SCAN_BLK / 2; off; off >>= 1) {
        if (threadIdx.x < off) s[threadIdx.x] += s[threadIdx.x + off];
        __syncthreads();
    }
    if (threadIdx.x == 0) bsum[blockIdx.x] = s[0];
}

// ---- scan stage 2: exclusive scan of block sums ----
__global__ void scan2_kernel(const int* __restrict__ bsum, int* __restrict__ boff) {
    __shared__ int s[128];
    const int tid = threadIdx.x;
    int v = (tid < NB1) ? bsum[tid] : 0;
    s[tid] = v;
    __syncthreads();
    for (int off = 1; off < 128; off <<= 1) {
        int t = (tid >= off) ? s[tid - off] : 0;
        __syncthreads();
        s[tid] += t;
        __syncthreads();
    }
    if (tid < NB1) boff[tid] = s[tid] - v;   // exclusive
}

// ---- scan stage 3: per-block exclusive scan + offset -> row_ptr, wp ----
__global__ void scan3_kernel(const int* __restrict__ counts, const int* __restrict__ boff,
                             int* __restrict__ row_ptr, int* __restrict__ wp) {
    __shared__ int s[SCAN_BLK];
    const int tid = threadIdx.x;
    const int i = blockIdx.x * SCAN_BLK + tid;
    const int v = counts[i];
    s[tid] = v;
    __syncthreads();
    for (int off = 1; off < SCAN_BLK; off <<= 1) {
        int t = (tid >= off) ? s[tid - off] : 0;
        __syncthreads();
        s[tid] += t;
        __syncthreads();
    }
    const int excl = boff[blockIdx.x] + s[tid] - v;
    if (i <= NNODES) row_ptr[i] = excl;
    if (i < NNODES)  wp[i] = excl;
}

// ---- XCD-partitioned fill: partition r writes e8 slots only for dst in its range ----
// per-XCD write region ~1.6 MB << 4 MB L2 -> lines accumulate fully before eviction
__global__ void fill8_kernel(const int* __restrict__ edge_index,
                             const int* __restrict__ dstm,
                             const int* __restrict__ wbuf,
                             int* __restrict__ wp,
                             int2* __restrict__ e8) {
    const int r = blockIdx.x & 7;
    const int c = blockIdx.x >> 3;
    const int lo = r * DPP, hi = lo + DPP;
    const int base = c * CHUNK;
    #pragma unroll
    for (int k = 0; k < CHUNK / 256; ++k) {
        const int e = base + k * 256 + threadIdx.x;
        if (e < NEDGES) {
            const int d = dstm[e];
            if (d >= lo && d < hi) {
                const int pos = atomicAdd(&wp[d], 1);
                e8[pos] = make_int2(edge_index[e], wbuf[e]);
            }
        }
    }
}

// ---- gather + fused hardtanh update: 64 lanes (1 wave) per node ----
#define CH 8
__global__ void gather_kernel(const float* __restrict__ x,
                              const int* __restrict__ row_ptr,
                              const int2* __restrict__ e8,
                              const float* __restrict__ S,
                              float* __restrict__ out) {
    const int gid = blockIdx.x * blockDim.x + threadIdx.x;
    const int node = gid >> 6;
    const int lane = threadIdx.x & 63;
    const int f = lane & 31;
    const int h = lane >> 5;
    if (node >= NNODES) return;
    const int beg = row_ptr[node];
    const int end = row_ptr[node + 1];
    const float xi = x[node * FEAT + f];

    float a0 = 0.0f, a1 = 0.0f;
    const int em1 = end - 1;
    for (int e = beg + CH * h; e < end; e += 2 * CH) {
        int2 s[CH];
        #pragma unroll
        for (int k = 0; k < CH; ++k) s[k] = e8[min(e + k, em1)];
        #pragma unroll
        for (int k = 0; k < CH; ++k) {
            const float v = x[s[k].x * FEAT + f];
            const float w = (e + k < end) ? __int_as_float(s[k].y) : 0.0f;
            if (k & 1) a1 = fmaf(w, v, a1);
            else       a0 = fmaf(w, v, a0);
        }
    }
    float acc = a0 + a1;
    acc += __shfl_xor(acc, 32);          // combine the two halves
    if (node == 0) acc += S[0] * x[f];   // masked-edge bulk contribution
    const float d = fminf(fmaxf(acc - xi, -1.0f), 1.0f);
    if (h == 0) out[node * FEAT + f] = fminf(fmaxf(xi + d, 0.0f), 2.0f);
}

extern "C" void kernel_launch(void* const* d_in, const int* in_sizes, int n_in,
                              void* d_out, int out_size, void* d_ws, size_t ws_size,
                              hipStream_t stream) {
    const float* x0         = (const float*)d_in[0];
    const int*   edge_index = (const int*)d_in[1];
    const int*   edge_mask  = (const int*)d_in[2];
    const float* edge_scale = (const float*)d_in[3];
    const float* pert_mask  = (const float*)d_in[4];
    const float* edge_weight= (const float*)d_in[5];
    float* xout = (float*)d_out;

    // ---- workspace layout ----
    char* ws = (char*)d_ws;
    float* S      = (float*)(ws);                            // 4 B
    float* S_part = (float*)(ws + 1024);                     // 12500 floats (50 KB)
    int*   counts = (int*)(ws + 64 * 1024);                  // NPAD ints (401 KB)
    int*   bsum   = (int*)(ws + 512 * 1024);                 // 98 ints
    int*   boff   = (int*)(ws + 512 * 1024 + 1024);          // 98 ints
    int*   row_ptr= (int*)(ws + 768 * 1024);                 // 100001 ints
    int*   wp     = (int*)(ws + 1536 * 1024);                // 100000 ints
    float* x_mid  = (float*)(ws + 2  * 1024 * 1024);         // 12.8 MB
    int2*  e8     = (int2*)(ws + 15 * 1024 * 1024);          // ~12.8 MB used (14 MB reserved)
    int*   wbuf   = (int*)(ws + 29 * 1024 * 1024);           // 12.8 MB
    int*   dstm   = (int*)(ws + 42 * 1024 * 1024);           // 12.8 MB
    // total ~55 MB

    hipMemsetAsync(counts, 0, (size_t)NPAD * sizeof(int), stream);

    ws_kernel<<<EDGE_BLOCKS, 256, 0, stream>>>(edge_index, edge_mask, edge_scale,
                                               pert_mask, edge_weight, dstm, wbuf, S_part);
    sreduce_kernel<<<1, 1024, 0, stream>>>(S_part, S);
    hist8_kernel<<<NPART * BPP, 256, 0, stream>>>(dstm, counts);
    scan1_kernel<<<NB1, SCAN_BLK, 0, stream>>>(counts, bsum);
    scan2_kernel<<<1, 128, 0, stream>>>(bsum, boff);
    scan3_kernel<<<NB1, SCAN_BLK, 0, stream>>>(counts, boff, row_ptr, wp);
    fill8_kernel<<<NPART * BPP, 256, 0, stream>>>(edge_index, dstm, wbuf, wp, e8);

    // 5 gather iterations, ping-pong: x0 -> out -> mid -> out -> mid -> out
    const int gblocks = (NNODES * 64) / 256;   // 25000, exact
    const float* cur = x0;
    float* bufs[NITER] = { xout, x_mid, xout, x_mid, xout };
    for (int it = 0; it < NITER; ++it) {
        gather_kernel<<<gblocks, 256, 0, stream>>>(cur, row_ptr, e8, S, bufs[it]);
        cur = bufs[it];
    }
}

// Round 5
// 324.135 us; speedup vs baseline: 1.3173x; 1.3173x over previous
//
#include <hip/hip_runtime.h>

#define NNODES 100000
#define NEDGES 3200000
#define FEAT 32
#define NITER 5
#define NF (NNODES * FEAT)

#define EDGE_BLOCKS (NEDGES / 256)     // 12500, exact

// bucket partition
#define BUCK_SH 7
#define BUCK_SZ 128                    // dsts per bucket
#define NBK 782                        // ceil(100000/128)
#define CHUNKF 8192                    // edges per fill block
#define NBF 391                        // ceil(3.2M/8192): 391*8192 = 3,203,072
#define NT (NBF * NBK)                 // 305,762 matrix elements
#define NTB 299                        // ceil(NT/1024)

// ---- pass A: per-edge weight + masked dst array + masked-weight partials ----
__global__ void ws_kernel(const int* __restrict__ edge_index,
                          const int* __restrict__ edge_mask,
                          const float* __restrict__ edge_scale,
                          const float* __restrict__ pert_mask,
                          const float* __restrict__ edge_weight,
                          int* __restrict__ dstm,
                          int* __restrict__ wbuf,
                          float* __restrict__ S_part) {
    const int e = blockIdx.x * 256 + threadIdx.x;   // grid covers NEDGES exactly
    const int m = edge_mask[e];
    const float w = (edge_weight[e] * (1.0f - pert_mask[e]) + pert_mask[e]) * edge_scale[e];
    wbuf[e] = __float_as_int(w);
    dstm[e] = m ? edge_index[NEDGES + e] : -1;
    float ms = m ? 0.0f : w;
    __shared__ float s[256];
    s[threadIdx.x] = ms;
    __syncthreads();
    for (int off = 128; off; off >>= 1) {
        if (threadIdx.x < off) s[threadIdx.x] += s[threadIdx.x + off];
        __syncthreads();
    }
    if (threadIdx.x == 0) S_part[blockIdx.x] = s[0];
}

__global__ void sreduce_kernel(const float* __restrict__ S_part, float* __restrict__ S) {
    __shared__ float s[1024];
    float a = 0.0f;
    for (int i = threadIdx.x; i < EDGE_BLOCKS; i += 1024) a += S_part[i];
    s[threadIdx.x] = a;
    __syncthreads();
    for (int off = 512; off; off >>= 1) {
        if (threadIdx.x < off) s[threadIdx.x] += s[threadIdx.x + off];
        __syncthreads();
    }
    if (threadIdx.x == 0) *S = s[0];
}

// ---- per-(block,bucket) histogram matrix: M[b*NBK + k] ----
__global__ void histmat_kernel(const int* __restrict__ dstm, int* __restrict__ M) {
    __shared__ int h[NBK];
    const int b = blockIdx.x;
    for (int k = threadIdx.x; k < NBK; k += 256) h[k] = 0;
    __syncthreads();
    const int base = b * CHUNKF;
    #pragma unroll
    for (int it = 0; it < CHUNKF / 256; ++it) {
        const int e = base + it * 256 + threadIdx.x;
        if (e < NEDGES) {
            const int d = dstm[e];
            if (d >= 0) atomicAdd(&h[d >> BUCK_SH], 1);
        }
    }
    __syncthreads();
    for (int k = threadIdx.x; k < NBK; k += 256) M[b * NBK + k] = h[k];
}

// ---- 3-stage exclusive scan over M in bucket-major (transposed) order ----
// T[i] = M[(i % NBF)*NBK + (i / NBF)]  for i in [0, NT)
__global__ void tscan1_kernel(const int* __restrict__ M, int* __restrict__ tb) {
    __shared__ int s[1024];
    const int i = blockIdx.x * 1024 + threadIdx.x;
    int v = 0;
    if (i < NT) v = M[(i % NBF) * NBK + (i / NBF)];
    s[threadIdx.x] = v;
    __syncthreads();
    for (int off = 512; off; off >>= 1) {
        if (threadIdx.x < off) s[threadIdx.x] += s[threadIdx.x + off];
        __syncthreads();
    }
    if (threadIdx.x == 0) tb[blockIdx.x] = s[0];
}

__global__ void tscan2_kernel(const int* __restrict__ tb, int* __restrict__ tboff,
                              int* __restrict__ bucket_base) {
    __shared__ int s[512];
    const int tid = threadIdx.x;
    int v = (tid < NTB) ? tb[tid] : 0;
    s[tid] = v;
    __syncthreads();
    for (int off = 1; off < 512; off <<= 1) {
        int t = (tid >= off) ? s[tid - off] : 0;
        __syncthreads();
        s[tid] += t;
        __syncthreads();
    }
    if (tid < NTB) tboff[tid] = s[tid] - v;     // exclusive
    if (tid == 511) bucket_base[NBK] = s[511];  // total unmasked edges
}

__global__ void tscan3_kernel(const int* __restrict__ M, const int* __restrict__ tboff,
                              int* __restrict__ scanT, int* __restrict__ bucket_base) {
    __shared__ int s[1024];
    const int tid = threadIdx.x;
    const int i = blockIdx.x * 1024 + tid;
    int v = 0;
    if (i < NT) v = M[(i % NBF) * NBK + (i / NBF)];
    s[tid] = v;
    __syncthreads();
    for (int off = 1; off < 1024; off <<= 1) {
        int t = (tid >= off) ? s[tid - off] : 0;
        __syncthreads();
        s[tid] += t;
        __syncthreads();
    }
    if (i < NT) {
        const int excl = tboff[blockIdx.x] + s[tid] - v;
        scanT[i] = excl;
        if (i % NBF == 0) bucket_base[i / NBF] = excl;
    }
}

// ---- fill: scatter (src | dstl<<20, w) to matrix offsets; no global atomics ----
__global__ void fill782_kernel(const int* __restrict__ edge_index,
                               const int* __restrict__ dstm,
                               const int* __restrict__ wbuf,
                               const int* __restrict__ scanT,
                               int2* __restrict__ e8tmp) {
    __shared__ int off[NBK];
    const int b = blockIdx.x;
    for (int k = threadIdx.x; k < NBK; k += 256) off[k] = scanT[k * NBF + b];
    __syncthreads();
    const int base = b * CHUNKF;
    #pragma unroll
    for (int it = 0; it < CHUNKF / 256; ++it) {
        const int e = base + it * 256 + threadIdx.x;
        if (e < NEDGES) {
            const int d = dstm[e];
            if (d >= 0) {
                const int k = d >> BUCK_SH;
                const int dstl = d & (BUCK_SZ - 1);
                const int pos = atomicAdd(&off[k], 1);
                e8tmp[pos] = make_int2(edge_index[e] | (dstl << 20), wbuf[e]);
            }
        }
    }
}

// ---- bucket sort: one block per bucket; LDS counting sort by local dst ----
// emits final dst-sorted e8 and row_ptr
__global__ void bsort_kernel(const int2* __restrict__ e8tmp,
                             const int* __restrict__ bucket_base,
                             int2* __restrict__ e8,
                             int* __restrict__ row_ptr) {
    __shared__ int h[BUCK_SZ];
    __shared__ int s[BUCK_SZ];
    __shared__ int woff[BUCK_SZ];
    const int k = blockIdx.x;
    const int tid = threadIdx.x;
    const int base0 = bucket_base[k];
    const int cnt = bucket_base[k + 1] - base0;
    if (tid < BUCK_SZ) h[tid] = 0;
    __syncthreads();
    for (int i = tid; i < cnt; i += 256) {
        const int dstl = e8tmp[base0 + i].x >> 20;
        atomicAdd(&h[dstl], 1);
    }
    __syncthreads();
    // inclusive scan of h into s (Hillis-Steele over 128)
    if (tid < BUCK_SZ) s[tid] = h[tid];
    __syncthreads();
    for (int off = 1; off < BUCK_SZ; off <<= 1) {
        int t = 0;
        if (tid < BUCK_SZ && tid >= off) t = s[tid - off];
        __syncthreads();
        if (tid < BUCK_SZ) s[tid] += t;
        __syncthreads();
    }
    if (tid < BUCK_SZ) {
        const int excl = s[tid] - h[tid];
        const int d = k * BUCK_SZ + tid;
        if (d < NNODES) row_ptr[d] = base0 + excl;
        woff[tid] = excl;
    }
    if (k == NBK - 1 && tid == 0) row_ptr[NNODES] = bucket_base[NBK];
    __syncthreads();
    for (int i = tid; i < cnt; i += 256) {
        const int2 v = e8tmp[base0 + i];
        const int dstl = v.x >> 20;
        const int src = v.x & 0xFFFFF;
        const int pos = atomicAdd(&woff[dstl], 1);
        e8[base0 + pos] = make_int2(src, v.y);
    }
}

// ---- gather + fused hardtanh update: 64 lanes (1 wave) per node ----
#define CH 8
__global__ void gather_kernel(const float* __restrict__ x,
                              const int* __restrict__ row_ptr,
                              const int2* __restrict__ e8,
                              const float* __restrict__ S,
                              float* __restrict__ out) {
    const int gid = blockIdx.x * blockDim.x + threadIdx.x;
    const int node = gid >> 6;
    const int lane = threadIdx.x & 63;
    const int f = lane & 31;
    const int h = lane >> 5;
    if (node >= NNODES) return;
    const int beg = row_ptr[node];
    const int end = row_ptr[node + 1];
    const float xi = x[node * FEAT + f];

    float a0 = 0.0f, a1 = 0.0f;
    const int em1 = end - 1;
    for (int e = beg + CH * h; e < end; e += 2 * CH) {
        int2 s[CH];
        #pragma unroll
        for (int kk = 0; kk < CH; ++kk) s[kk] = e8[min(e + kk, em1)];
        #pragma unroll
        for (int kk = 0; kk < CH; ++kk) {
            const float v = x[s[kk].x * FEAT + f];
            const float w = (e + kk < end) ? __int_as_float(s[kk].y) : 0.0f;
            if (kk & 1) a1 = fmaf(w, v, a1);
            else        a0 = fmaf(w, v, a0);
        }
    }
    float acc = a0 + a1;
    acc += __shfl_xor(acc, 32);          // combine the two halves
    if (node == 0) acc += S[0] * x[f];   // masked-edge bulk contribution
    const float d = fminf(fmaxf(acc - xi, -1.0f), 1.0f);
    if (h == 0) out[node * FEAT + f] = fminf(fmaxf(xi + d, 0.0f), 2.0f);
}

extern "C" void kernel_launch(void* const* d_in, const int* in_sizes, int n_in,
                              void* d_out, int out_size, void* d_ws, size_t ws_size,
                              hipStream_t stream) {
    const float* x0         = (const float*)d_in[0];
    const int*   edge_index = (const int*)d_in[1];
    const int*   edge_mask  = (const int*)d_in[2];
    const float* edge_scale = (const float*)d_in[3];
    const float* pert_mask  = (const float*)d_in[4];
    const float* edge_weight= (const float*)d_in[5];
    float* xout = (float*)d_out;

    // ---- workspace layout ----
    char* ws = (char*)d_ws;
    float* S        = (float*)(ws);                          // 4 B
    float* S_part   = (float*)(ws + 1024);                   // 12500 floats
    int*   tb       = (int*)(ws + 64 * 1024);                // 299 ints
    int*   tboff    = (int*)(ws + 68 * 1024);                // 299 ints
    int*   bbase    = (int*)(ws + 72 * 1024);                // 783 ints
    int*   row_ptr  = (int*)(ws + 80 * 1024);                // 100001 ints
    int*   M        = (int*)(ws + 512 * 1024);               // NT ints (1.22 MB)
    int*   scanT    = (int*)(ws + 2  * 1024 * 1024);         // NT ints (1.22 MB)
    float* x_mid    = (float*)(ws + 4  * 1024 * 1024);       // 12.8 MB
    int2*  e8tmp    = (int2*)(ws + 17 * 1024 * 1024);        // 12.8 MB
    int2*  e8       = (int2*)(ws + 30 * 1024 * 1024);        // 12.8 MB
    int*   wbuf     = (int*)(ws + 43 * 1024 * 1024);         // 12.8 MB
    int*   dstm     = (int*)(ws + 56 * 1024 * 1024);         // 12.8 MB
    // total ~69 MB

    ws_kernel<<<EDGE_BLOCKS, 256, 0, stream>>>(edge_index, edge_mask, edge_scale,
                                               pert_mask, edge_weight, dstm, wbuf, S_part);
    sreduce_kernel<<<1, 1024, 0, stream>>>(S_part, S);
    histmat_kernel<<<NBF, 256, 0, stream>>>(dstm, M);
    tscan1_kernel<<<NTB, 1024, 0, stream>>>(M, tb);
    tscan2_kernel<<<1, 512, 0, stream>>>(tb, tboff, bbase);
    tscan3_kernel<<<NTB, 1024, 0, stream>>>(M, tboff, scanT, bbase);
    fill782_kernel<<<NBF, 256, 0, stream>>>(edge_index, dstm, wbuf, scanT, e8tmp);
    bsort_kernel<<<NBK, 256, 0, stream>>>(e8tmp, bbase, e8, row_ptr);

    // 5 gather iterations, ping-pong: x0 -> out -> mid -> out -> mid -> out
    const int gblocks = (NNODES * 64) / 256;   // 25000, exact
    const float* cur = x0;
    float* bufs[NITER] = { xout, x_mid, xout, x_mid, xout };
    for (int it = 0; it < NITER; ++it) {
        gather_kernel<<<gblocks, 256, 0, stream>>>(cur, row_ptr, e8, S, bufs[it]);
        cur = bufs[it];
    }
}